// Round 3
// baseline (652.148 us; speedup 1.0000x reference)
//
#include <hip/hip_runtime.h>
#include <stdint.h>

typedef unsigned short u16;
typedef __bf16 bf16x8 __attribute__((ext_vector_type(8)));
typedef float f32x4 __attribute__((ext_vector_type(4)));
typedef unsigned short u16x8 __attribute__((ext_vector_type(8)));

#define MFMA16(a, b, c) __builtin_amdgcn_mfma_f32_16x16x32_bf16((a), (b), (c), 0, 0, 0)

// B=4, N=8192, DIM=1024, H=16, DH=64, W=128 -> NW=64 windows, INNER=1024
#define SEQ_N 8192
#define NWIN 64

#define BAR() __builtin_amdgcn_s_barrier()
#define PRIO1() __builtin_amdgcn_s_setprio(1)
#define PRIO0() __builtin_amdgcn_s_setprio(0)
#define SB0() __builtin_amdgcn_sched_barrier(0)
#define VM8() asm volatile("s_waitcnt vmcnt(8)" ::: "memory")
#define VM0() asm volatile("s_waitcnt vmcnt(0)" ::: "memory")
#define LGKM0() asm volatile("s_waitcnt lgkmcnt(0)" ::: "memory")

__device__ __forceinline__ u16 f2bf(float f) {
  union { float f; uint32_t u; } v; v.f = f;
  return (u16)((v.u + 0x7fffu + ((v.u >> 16) & 1u)) >> 16);  // RNE
}

__device__ __forceinline__ void load_lds16(const void* g, void* l) {
  // async global->LDS, 16B/lane; LDS dest = wave-uniform base + lane*16
  __builtin_amdgcn_global_load_lds((const __attribute__((address_space(1))) void*)g,
                                   (__attribute__((address_space(3))) void*)l, 16, 0, 0);
}

// ---------------- cast fp32 -> bf16, 8 elems/thread ----------------
__global__ __launch_bounds__(256) void cast_bf16_kernel(const float* __restrict__ src,
                                                        u16* __restrict__ dst, int n8) {
  int i = blockIdx.x * 256 + threadIdx.x;
  if (i >= n8) return;
  const float4* s = (const float4*)src + (size_t)i * 2;
  float4 a = s[0], b = s[1];
  u16x8 o;
  o[0] = f2bf(a.x); o[1] = f2bf(a.y); o[2] = f2bf(a.z); o[3] = f2bf(a.w);
  o[4] = f2bf(b.x); o[5] = f2bf(b.y); o[6] = f2bf(b.z); o[7] = f2bf(b.w);
  *((u16x8*)dst + i) = o;
}

// ------------- transpose + cast: dst[n][k] = src[k][n] (bf16) -------------
__global__ __launch_bounds__(256) void transpose_cast_kernel(u16* __restrict__ dst,
                                                             const float* __restrict__ srcA,
                                                             const float* __restrict__ srcB,
                                                             int bcols) {
  __shared__ float tile[32][33];
  const int tx = threadIdx.x & 31, ty = threadIdx.x >> 5;  // ty 0..7
  const int n0 = blockIdx.x * 32, k0 = blockIdx.y * 32;
#pragma unroll
  for (int i = 0; i < 4; ++i) {
    int k = k0 + ty + i * 8;
    int n = n0 + tx;
    float v = (n < 1024) ? srcA[(size_t)k * 1024 + n]
                         : srcB[(size_t)k * bcols + (n - 1024)];
    tile[ty + i * 8][tx] = v;
  }
  __syncthreads();
#pragma unroll
  for (int i = 0; i < 4; ++i) {
    int n = n0 + ty + i * 8;
    int k = k0 + tx;
    dst[(size_t)n * 1024 + k] = f2bf(tile[tx][ty + i * 8]);
  }
}

// ================= 256^2 pipelined GEMM (m201-derived) =============
// Schedule byte-identical to round-2 (proven race-free). This round only the
// ADDRESSING changes:
//  MODE 0 (QKV): epilogue writes q/k/v HEAD-MAJOR [B][H][8192][64]
//                (offset = ((b*16+h)<<19) + (n<<6) + d) -> attention panels
//                become contiguous; epilogue token stride drops 2KB -> 128B.
//  MODE 1 (WO):  A (= attn output) is consumed head-major. BK=64 == one head,
//                so K-tile index == head index; 128B row granule preserved ->
//                LDS layout, T2 swizzle, ds_reads all unchanged.
#define READ_A_TO(dst, MH)                                                         \
  _Pragma("unroll") for (int kk = 0; kk < 2; ++kk)                                 \
  _Pragma("unroll") for (int m = 0; m < 4; ++m)                                    \
    dst[m][kk] = *(const bf16x8*)(Ard + bo + (((MH) * 64 + m * 16) << 7) + ax[kk]);

#define READ_B_TO(dst, NH)                                                         \
  _Pragma("unroll") for (int kk = 0; kk < 2; ++kk)                                 \
  _Pragma("unroll") for (int n = 0; n < 2; ++n)                                    \
    dst[n][kk] = *(const bf16x8*)(Brd + bo + (((NH) * 32 + n * 16) << 7) + ax[kk]);

#define MFMAQ(fa, fb, MH, NH)                                                      \
  _Pragma("unroll") for (int kk = 0; kk < 2; ++kk)                                 \
  _Pragma("unroll") for (int m = 0; m < 4; ++m)                                    \
  _Pragma("unroll") for (int n = 0; n < 2; ++n)                                    \
    acc[(MH) * 4 + m][(NH) * 2 + n] =                                              \
        MFMA16(fa[m][kk], fb[n][kk], acc[(MH) * 4 + m][(NH) * 2 + n]);

template <int NBN, int MODE>
__global__ __launch_bounds__(512, 2) void gemm8_kernel(
    const u16* __restrict__ A, const u16* __restrict__ Bt,
    u16* __restrict__ qo, u16* __restrict__ ko, u16* __restrict__ vo,
    float* __restrict__ out, const float* __restrict__ bias) {
  extern __shared__ char smem[];  // 128 KiB: A[2][256][64] | B[2][256][64] bf16
  constexpr int K = 1024;
  constexpr int NT = K / 64;  // 16 K-tiles
  const int tid = threadIdx.x;
  const int wave = tid >> 6, lane = tid & 63;
  const int quad = lane >> 4, l15 = lane & 15;
  const int wm = wave >> 2, wn = wave & 3;

  // bijective XCD swizzle: NBM=128=8 XCDs x 16; within an XCD, bn-major.
  const int idx0 = blockIdx.x;
  const int local = idx0 >> 3;
  const int bn = local >> 4;
  const int bm = ((idx0 & 7) << 4) + (local & 15);

  char* const Ab = smem;
  char* const Bb = smem + 65536;

  // staging: linear LDS dest, inverse-swizzled global source (rule 21)
  const int sr = lane >> 3;
  const int sg = ((lane & 7) ^ sr) * 8;  // u16 elems, < 64
  const u16* const gA = A + (size_t)(bm * 256 + wave * 32 + sr) * K + sg;
  const u16* const gB = Bt + (size_t)(bn * 256 + wave * 32 + sr) * K + sg;
  // head-major A addressing (MODE 1): b = bm>>5 (256-row block never crosses b)
  const size_t aN = (size_t)((bm & 31) * 256 + wave * 32 + sr);  // n within b
  const int ab16 = (bm >> 5) * 16;
  char* const lA = Ab + wave * 32 * 128;  // this wave stages rows [w*32, w*32+32)
  char* const lB = Bb + wave * 32 * 128;

  auto stage = [&](int buf, int kt) {
    if constexpr (MODE == 0) {
#pragma unroll
      for (int i = 0; i < 4; ++i)
        load_lds16(gA + (size_t)kt * 64 + i * 8 * K, lA + buf * 32768 + i * 1024);
    } else {
      const u16* g = A + (((size_t)(ab16 + kt)) << 19) + (aN << 6) + sg;
#pragma unroll
      for (int i = 0; i < 4; ++i)
        load_lds16(g + i * 512, lA + buf * 32768 + i * 1024);  // 8 rows x 64 elems
    }
#pragma unroll
    for (int i = 0; i < 4; ++i)
      load_lds16(gB + (size_t)kt * 64 + i * 8 * K, lB + buf * 32768 + i * 1024);
  };

  // fragment reads: swizzled column byte (row&7 == l15&7 here)
  const int ax[2] = { (quad ^ (l15 & 7)) << 4, ((quad ^ (l15 & 7)) << 4) ^ 64 };
  const char* const Ard = Ab + ((wm * 128 + l15) << 7);
  const char* const Brd = Bb + ((wn * 64 + l15) << 7);

  f32x4 acc[8][4] = {};
  bf16x8 afA[4][2], afB[4][2], bf0[2][2], bf1[2][2];

  stage(0, 0);
  stage(1, 1);
  VM8();  // tile 0's 8 loads done; tile 1's 8 in flight
  BAR();

  for (int kt = 0; kt < NT; ++kt) {
    const int bo = (kt & 1) * 32768;
    READ_A_TO(afA, 0)
    READ_B_TO(bf0, 0)
    READ_B_TO(bf1, 1)
    SB0();
    PRIO1(); MFMAQ(afA, bf0, 0, 0) PRIO0();
    BAR();
    READ_A_TO(afB, 1)
    SB0();
    PRIO1(); MFMAQ(afA, bf1, 0, 1) PRIO0();
    BAR();
    PRIO1(); MFMAQ(afB, bf1, 1, 1) PRIO0();
    LGKM0();  // all this wave's reads of buf complete
    BAR();    // => ALL waves done reading buf; safe to overwrite
    if (kt + 2 < NT) stage(kt & 1, kt + 2);
    PRIO1(); MFMAQ(afB, bf0, 1, 0) PRIO0();
    if (kt < NT - 1) {
      if (kt + 2 < NT) { VM8(); } else { VM0(); }
      BAR();
    }
  }

  // ---- epilogue ----
  const int row0 = bm * 256 + wm * 128;
#pragma unroll
  for (int mt = 0; mt < 8; ++mt) {
#pragma unroll
    for (int nt = 0; nt < 4; ++nt) {
      if (MODE == 0) {
        // head-major write: off = ((b*16+h)<<19) + (n<<6) + d
        const int col = bn * 256 + wn * 64 + nt * 16 + l15;
        u16* dst = (col < 1024) ? qo : ((col < 2048) ? ko : vo);
        const int cc = col & 1023;
        const size_t hb = (((size_t)(ab16 + (cc >> 6))) << 19) + (size_t)(cc & 63);
        const int nb = (bm & 31) * 256 + wm * 128 + mt * 16 + quad * 4;
#pragma unroll
        for (int r = 0; r < 4; ++r)
          dst[hb + ((size_t)(nb + r) << 6)] = f2bf(acc[mt][nt][r]);
      } else {
        const int col = bn * 256 + wn * 64 + nt * 16 + l15;
        const float bv = bias[col];
#pragma unroll
        for (int r = 0; r < 4; ++r) {
          const int row = row0 + mt * 16 + quad * 4 + r;
          out[(size_t)row * 1024 + col] = acc[mt][nt][r] + bv;
        }
      }
    }
  }
}

// ---------------- windowed attention (head-major q/k/v this round) ----------------
// q/k/v/o all [B][H][8192][64] head-major: per-block panels are CONTIGUOUS
// (Q 16KB, K/V 32KB; K panel L1-resident for the 4-wave redundant reads).
__global__ __launch_bounds__(256, 2) void attn_kernel(const u16* __restrict__ qb,
                                                      const u16* __restrict__ kb,
                                                      const u16* __restrict__ vb,
                                                      u16* __restrict__ ob) {
  __shared__ u16 Vt[64][264];      // [d][token], +8 pad
  __shared__ u16 Ps[4 * 2048];     // per-wave double-buffered 32x32 P chunk
  const int tid = threadIdx.x;
  const int wave = tid >> 6, lane = tid & 63;
  const int quad = lane >> 4, l15 = lane & 15;
  // bijective XCD swizzle (4096 = 8 x 512): adjacent windows share a K/V panel.
  const int raw = blockIdx.x;
  const int blk = ((raw & 7) << 9) | (raw >> 3);
  const int wi = blk & (NWIN - 1);
  const int bh = blk >> 6;                       // b*16 + h
  const long qbase = ((long)bh * SEQ_N + (long)wi * 128) * 64;
  const long kbase = ((long)bh * SEQ_N + (long)wi * 128 - 128) * 64;

  // ---- stage V transposed: thread t handles key token t (contiguous 128B row) ----
  {
    const int t = tid;
    const bool pad = (wi == 0) && (t < 128);
#pragma unroll
    for (int d0 = 0; d0 < 64; d0 += 8) {
      u16x8 v8;
      if (pad) {
        v8 = (u16x8)0;
      } else {
        v8 = *(const u16x8*)(vb + (kbase + (long)t * 64 + d0));
      }
#pragma unroll
      for (int j = 0; j < 8; ++j) Vt[d0 + j][t] = v8[j];
    }
  }

  // ---- Q fragments (A-operand, direct from global; rows 128B apart) ----
  bf16x8 qf[2][2];
#pragma unroll
  for (int mt = 0; mt < 2; ++mt)
#pragma unroll
    for (int kk = 0; kk < 2; ++kk)
      qf[mt][kk] = *(const bf16x8*)(qb + (qbase + (long)(wave * 32 + mt * 16 + l15) * 64 +
                                          kk * 32 + quad * 8));

  // ---- S = Q K^T ----
  f32x4 s[2][16] = {};
#pragma unroll
  for (int nt = 0; nt < 16; ++nt) {
    if (!((wi == 0) && (nt < 8))) {  // zero-pad keys -> s stays 0
      const long kt = kbase + (long)(nt * 16 + l15) * 64;
      bf16x8 kf0 = *(const bf16x8*)(kb + (kt + quad * 8));
      bf16x8 kf1 = *(const bf16x8*)(kb + (kt + 32 + quad * 8));
#pragma unroll
      for (int mt = 0; mt < 2; ++mt) {
        s[mt][nt] = MFMA16(qf[mt][0], kf0, s[mt][nt]);
        s[mt][nt] = MFMA16(qf[mt][1], kf1, s[mt][nt]);
      }
    }
  }

  // ---- masked softmax over 256 keys ----
#pragma unroll
  for (int mt = 0; mt < 2; ++mt) {
#pragma unroll
    for (int r = 0; r < 4; ++r) {
      const int row = wave * 32 + mt * 16 + quad * 4 + r;
      float m = -3.0e38f;
#pragma unroll
      for (int nt = 0; nt < 16; ++nt) {
        const int col = nt * 16 + l15;
        float x = s[mt][nt][r] * 0.125f;   // dh^-0.5
        if (col > row + 128) x = -3.0e38f; // causal: key j visible iff j <= i+128
        s[mt][nt][r] = x;
        m = fmaxf(m, x);
      }
      m = fmaxf(m, __shfl_xor(m, 1));
      m = fmaxf(m, __shfl_xor(m, 2));
      m = fmaxf(m, __shfl_xor(m, 4));
      m = fmaxf(m, __shfl_xor(m, 8));
      float sum = 0.f;
#pragma unroll
      for (int nt = 0; nt < 16; ++nt) {
        float e = __expf(s[mt][nt][r] - m);
        s[mt][nt][r] = e;
        sum += e;
      }
      sum += __shfl_xor(sum, 1);
      sum += __shfl_xor(sum, 2);
      sum += __shfl_xor(sum, 4);
      sum += __shfl_xor(sum, 8);
      const float inv = 1.0f / sum;
#pragma unroll
      for (int nt = 0; nt < 16; ++nt) s[mt][nt][r] *= inv;
    }
  }

  __syncthreads();  // Vt ready for all waves

  // ---- O = P V : per 32-key chunk, bounce P through LDS into A-layout ----
  f32x4 o[2][4] = {};
#pragma unroll
  for (int ks = 0; ks < 8; ++ks) {
    u16* myP = &Ps[wave * 2048 + (ks & 1) * 1024];  // 32 rows x 32 cols bf16
#pragma unroll
    for (int mt = 0; mt < 2; ++mt)
#pragma unroll
      for (int half = 0; half < 2; ++half) {
        const int nt = ks * 2 + half;
#pragma unroll
        for (int r = 0; r < 4; ++r)
          myP[(mt * 16 + quad * 4 + r) * 32 + half * 16 + l15] = f2bf(s[mt][nt][r]);
      }
    bf16x8 pf[2];
    pf[0] = *(const bf16x8*)&myP[l15 * 32 + quad * 8];
    pf[1] = *(const bf16x8*)&myP[(16 + l15) * 32 + quad * 8];
#pragma unroll
    for (int ont = 0; ont < 4; ++ont) {
      bf16x8 vf = *(const bf16x8*)&Vt[ont * 16 + l15][ks * 32 + quad * 8];
      o[0][ont] = MFMA16(pf[0], vf, o[0][ont]);
      o[1][ont] = MFMA16(pf[1], vf, o[1][ont]);
    }
  }

  // ---- write O head-major (token stride 128B) ----
#pragma unroll
  for (int mt = 0; mt < 2; ++mt)
#pragma unroll
    for (int ont = 0; ont < 4; ++ont)
#pragma unroll
      for (int r = 0; r < 4; ++r) {
        const int row = wave * 32 + mt * 16 + quad * 4 + r;
        const int col = ont * 16 + l15;
        ob[qbase + (long)row * 64 + col] = f2bf(o[mt][ont][r]);
      }
}

extern "C" void kernel_launch(void* const* d_in, const int* in_sizes, int n_in,
                              void* d_out, int out_size, void* d_ws, size_t ws_size,
                              hipStream_t stream) {
  const float* x   = (const float*)d_in[0];
  const float* wq  = (const float*)d_in[1];
  const float* wkv = (const float*)d_in[2];
  const float* wo  = (const float*)d_in[3];
  const float* bo  = (const float*)d_in[4];
  float* out = (float*)d_out;

  const size_t XE = (size_t)4 * SEQ_N * 1024;  // 33,554,432 tokens*dim elements
  u16* ws = (u16*)d_ws;
  u16* xb    = ws;            // bf16 x (reused as attention output buffer)
  u16* qbuf  = ws + XE;       // head-major [B][H][8192][64]
  u16* kbuf  = ws + 2 * XE;
  u16* vbuf  = ws + 3 * XE;
  u16* wqkvT = ws + 4 * XE;           // [3072][1024]
  u16* woT   = wqkvT + 3072 * 1024;   // [1024][1024]
  u16* obuf  = xb;                    // head-major attn output (xb dead after QKV)

  // allow 128 KiB dynamic LDS
  hipFuncSetAttribute(reinterpret_cast<const void*>(gemm8_kernel<12, 0>),
                      hipFuncAttributeMaxDynamicSharedMemorySize, 131072);
  hipFuncSetAttribute(reinterpret_cast<const void*>(gemm8_kernel<4, 1>),
                      hipFuncAttributeMaxDynamicSharedMemorySize, 131072);

  cast_bf16_kernel<<<16384, 256, 0, stream>>>(x, xb, (int)(XE / 8));
  transpose_cast_kernel<<<dim3(96, 32), 256, 0, stream>>>(wqkvT, wq, wkv, 2048);
  transpose_cast_kernel<<<dim3(32, 32), 256, 0, stream>>>(woT, wo, wo, 1024);
  // QKV: M=32768 (128 m-blocks), N=3072 (12 n-blocks) -> 1536 blocks
  gemm8_kernel<12, 0><<<1536, 512, 131072, stream>>>(xb, wqkvT, qbuf, kbuf, vbuf,
                                                     nullptr, nullptr);
  attn_kernel<<<4096, 256, 0, stream>>>(qbuf, kbuf, vbuf, obuf);
  // WO: N=1024 (4 n-blocks) -> 512 blocks; A consumed head-major
  gemm8_kernel<4, 1><<<512, 512, 131072, stream>>>(obuf, woT, nullptr, nullptr, nullptr,
                                                   out, bo);
}

// Round 4
// 612.138 us; speedup vs baseline: 1.0654x; 1.0654x over previous
//
#include <hip/hip_runtime.h>
#include <stdint.h>

typedef unsigned short u16;
typedef __bf16 bf16x8 __attribute__((ext_vector_type(8)));
typedef float f32x4 __attribute__((ext_vector_type(4)));
typedef unsigned short u16x8 __attribute__((ext_vector_type(8)));

#define MFMA16(a, b, c) __builtin_amdgcn_mfma_f32_16x16x32_bf16((a), (b), (c), 0, 0, 0)

// B=4, N=8192, DIM=1024, H=16, DH=64, W=128 -> NW=64 windows, INNER=1024
#define SEQ_N 8192
#define NWIN 64

#define BAR() __builtin_amdgcn_s_barrier()
#define PRIO1() __builtin_amdgcn_s_setprio(1)
#define PRIO0() __builtin_amdgcn_s_setprio(0)
#define SB0() __builtin_amdgcn_sched_barrier(0)
#define VM8() asm volatile("s_waitcnt vmcnt(8)" ::: "memory")
#define VM0() asm volatile("s_waitcnt vmcnt(0)" ::: "memory")
#define LGKM0() asm volatile("s_waitcnt lgkmcnt(0)" ::: "memory")

__device__ __forceinline__ u16 f2bf(float f) {
  union { float f; uint32_t u; } v; v.f = f;
  return (u16)((v.u + 0x7fffu + ((v.u >> 16) & 1u)) >> 16);  // RNE
}

__device__ __forceinline__ void load_lds16(const void* g, void* l) {
  // async global->LDS, 16B/lane; LDS dest = wave-uniform base + lane*16
  __builtin_amdgcn_global_load_lds((const __attribute__((address_space(1))) void*)g,
                                   (__attribute__((address_space(3))) void*)l, 16, 0, 0);
}

// ---------------- cast fp32 -> bf16, 8 elems/thread ----------------
__global__ __launch_bounds__(256) void cast_bf16_kernel(const float* __restrict__ src,
                                                        u16* __restrict__ dst, int n8) {
  int i = blockIdx.x * 256 + threadIdx.x;
  if (i >= n8) return;
  const float4* s = (const float4*)src + (size_t)i * 2;
  float4 a = s[0], b = s[1];
  u16x8 o;
  o[0] = f2bf(a.x); o[1] = f2bf(a.y); o[2] = f2bf(a.z); o[3] = f2bf(a.w);
  o[4] = f2bf(b.x); o[5] = f2bf(b.y); o[6] = f2bf(b.z); o[7] = f2bf(b.w);
  *((u16x8*)dst + i) = o;
}

// ------------- transpose + cast: dst[n][k] = src[k][n] (bf16) -------------
__global__ __launch_bounds__(256) void transpose_cast_kernel(u16* __restrict__ dst,
                                                             const float* __restrict__ srcA,
                                                             const float* __restrict__ srcB,
                                                             int bcols) {
  __shared__ float tile[32][33];
  const int tx = threadIdx.x & 31, ty = threadIdx.x >> 5;  // ty 0..7
  const int n0 = blockIdx.x * 32, k0 = blockIdx.y * 32;
#pragma unroll
  for (int i = 0; i < 4; ++i) {
    int k = k0 + ty + i * 8;
    int n = n0 + tx;
    float v = (n < 1024) ? srcA[(size_t)k * 1024 + n]
                         : srcB[(size_t)k * bcols + (n - 1024)];
    tile[ty + i * 8][tx] = v;
  }
  __syncthreads();
#pragma unroll
  for (int i = 0; i < 4; ++i) {
    int n = n0 + ty + i * 8;
    int k = k0 + tx;
    dst[(size_t)n * 1024 + k] = f2bf(tile[tx][ty + i * 8]);
  }
}

// ================= 256^2 pipelined GEMM (m201-derived) — UNCHANGED =============
#define READ_A_TO(dst, MH)                                                         \
  _Pragma("unroll") for (int kk = 0; kk < 2; ++kk)                                 \
  _Pragma("unroll") for (int m = 0; m < 4; ++m)                                    \
    dst[m][kk] = *(const bf16x8*)(Ard + bo + (((MH) * 64 + m * 16) << 7) + ax[kk]);

#define READ_B_TO(dst, NH)                                                         \
  _Pragma("unroll") for (int kk = 0; kk < 2; ++kk)                                 \
  _Pragma("unroll") for (int n = 0; n < 2; ++n)                                    \
    dst[n][kk] = *(const bf16x8*)(Brd + bo + (((NH) * 32 + n * 16) << 7) + ax[kk]);

#define MFMAQ(fa, fb, MH, NH)                                                      \
  _Pragma("unroll") for (int kk = 0; kk < 2; ++kk)                                 \
  _Pragma("unroll") for (int m = 0; m < 4; ++m)                                    \
  _Pragma("unroll") for (int n = 0; n < 2; ++n)                                    \
    acc[(MH) * 4 + m][(NH) * 2 + n] =                                              \
        MFMA16(fa[m][kk], fb[n][kk], acc[(MH) * 4 + m][(NH) * 2 + n]);

template <int NBN, int MODE>
__global__ __launch_bounds__(512, 2) void gemm8_kernel(
    const u16* __restrict__ A, const u16* __restrict__ Bt,
    u16* __restrict__ qo, u16* __restrict__ ko, u16* __restrict__ vo,
    float* __restrict__ out, const float* __restrict__ bias) {
  extern __shared__ char smem[];  // 128 KiB: A[2][256][64] | B[2][256][64] bf16
  constexpr int K = 1024;
  constexpr int NT = K / 64;  // 16 K-tiles
  const int tid = threadIdx.x;
  const int wave = tid >> 6, lane = tid & 63;
  const int quad = lane >> 4, l15 = lane & 15;
  const int wm = wave >> 2, wn = wave & 3;

  // bijective XCD swizzle: NBM=128=8 XCDs x 16; within an XCD, bn-major.
  const int idx0 = blockIdx.x;
  const int local = idx0 >> 3;
  const int bn = local >> 4;
  const int bm = ((idx0 & 7) << 4) + (local & 15);

  char* const Ab = smem;
  char* const Bb = smem + 65536;

  // staging: linear LDS dest, inverse-swizzled global source (rule 21)
  const int sr = lane >> 3;
  const int sg = ((lane & 7) ^ sr) * 8;  // u16 elems, < 64
  const u16* const gA = A + (size_t)(bm * 256 + wave * 32 + sr) * K + sg;
  const u16* const gB = Bt + (size_t)(bn * 256 + wave * 32 + sr) * K + sg;
  // head-major A addressing (MODE 1): b = bm>>5 (256-row block never crosses b)
  const size_t aN = (size_t)((bm & 31) * 256 + wave * 32 + sr);  // n within b
  const int ab16 = (bm >> 5) * 16;
  char* const lA = Ab + wave * 32 * 128;  // this wave stages rows [w*32, w*32+32)
  char* const lB = Bb + wave * 32 * 128;

  auto stage = [&](int buf, int kt) {
    if constexpr (MODE == 0) {
#pragma unroll
      for (int i = 0; i < 4; ++i)
        load_lds16(gA + (size_t)kt * 64 + i * 8 * K, lA + buf * 32768 + i * 1024);
    } else {
      const u16* g = A + (((size_t)(ab16 + kt)) << 19) + (aN << 6) + sg;
#pragma unroll
      for (int i = 0; i < 4; ++i)
        load_lds16(g + i * 512, lA + buf * 32768 + i * 1024);  // 8 rows x 64 elems
    }
#pragma unroll
    for (int i = 0; i < 4; ++i)
      load_lds16(gB + (size_t)kt * 64 + i * 8 * K, lB + buf * 32768 + i * 1024);
  };

  // fragment reads: swizzled column byte (row&7 == l15&7 here)
  const int ax[2] = { (quad ^ (l15 & 7)) << 4, ((quad ^ (l15 & 7)) << 4) ^ 64 };
  const char* const Ard = Ab + ((wm * 128 + l15) << 7);
  const char* const Brd = Bb + ((wn * 64 + l15) << 7);

  f32x4 acc[8][4] = {};
  bf16x8 afA[4][2], afB[4][2], bf0[2][2], bf1[2][2];

  stage(0, 0);
  stage(1, 1);
  VM8();  // tile 0's 8 loads done; tile 1's 8 in flight
  BAR();

  for (int kt = 0; kt < NT; ++kt) {
    const int bo = (kt & 1) * 32768;
    READ_A_TO(afA, 0)
    READ_B_TO(bf0, 0)
    READ_B_TO(bf1, 1)
    SB0();
    PRIO1(); MFMAQ(afA, bf0, 0, 0) PRIO0();
    BAR();
    READ_A_TO(afB, 1)
    SB0();
    PRIO1(); MFMAQ(afA, bf1, 0, 1) PRIO0();
    BAR();
    PRIO1(); MFMAQ(afB, bf1, 1, 1) PRIO0();
    LGKM0();  // all this wave's reads of buf complete
    BAR();    // => ALL waves done reading buf; safe to overwrite
    if (kt + 2 < NT) stage(kt & 1, kt + 2);
    PRIO1(); MFMAQ(afB, bf0, 1, 0) PRIO0();
    if (kt < NT - 1) {
      if (kt + 2 < NT) { VM8(); } else { VM0(); }
      BAR();
    }
  }

  // ---- epilogue ----
  const int row0 = bm * 256 + wm * 128;
#pragma unroll
  for (int mt = 0; mt < 8; ++mt) {
#pragma unroll
    for (int nt = 0; nt < 4; ++nt) {
      if (MODE == 0) {
        // head-major write: off = ((b*16+h)<<19) + (n<<6) + d
        const int col = bn * 256 + wn * 64 + nt * 16 + l15;
        u16* dst = (col < 1024) ? qo : ((col < 2048) ? ko : vo);
        const int cc = col & 1023;
        const size_t hb = (((size_t)(ab16 + (cc >> 6))) << 19) + (size_t)(cc & 63);
        const int nb = (bm & 31) * 256 + wm * 128 + mt * 16 + quad * 4;
#pragma unroll
        for (int r = 0; r < 4; ++r)
          dst[hb + ((size_t)(nb + r) << 6)] = f2bf(acc[mt][nt][r]);
      } else {
        const int col = bn * 256 + wn * 64 + nt * 16 + l15;
        const float bv = bias[col];
#pragma unroll
        for (int r = 0; r < 4; ++r) {
          const int row = row0 + mt * 16 + quad * 4 + r;
          out[(size_t)row * 1024 + col] = acc[mt][nt][r] + bv;
        }
      }
    }
  }
}

// ---------------- windowed attention v2: LDS-clean (this round) ----------------
// Changes vs round 3 (addressing only; fragment VALUES bit-identical):
//  1. K panel staged ONCE in LDS via global_load_lds with the GEMM's proven T2
//     pattern (linear dest + inverse-swizzled source + XOR'd ds_read_b128) --
//     kills the 4x-redundant latency-exposed global K loads per wave.
//  2. Vt XOR-swizzle (granule ^= d&7, pad removed): b128 reads + scalar writes
//     go 8-way-conflict -> 2/bank (free).
//  3. Ps XOR-swizzle (granule ^= (row>>2)&3): pf b128 reads 8-way -> free;
//     scalar writes 8-way -> 4-way.
//  One __syncthreads total (covers K staging vmcnt + V/Q); post-softmax barrier
//  removed (Vt is written before the same barrier; Ps is per-wave).
__global__ __launch_bounds__(256, 2) void attn_kernel(const u16* __restrict__ qb,
                                                      const u16* __restrict__ kb,
                                                      const u16* __restrict__ vb,
                                                      u16* __restrict__ ob) {
  __shared__ u16 Klds[256 * 64];   // [token][d], T2-swizzled (rows 128B)   32KB
  __shared__ u16 Vt[64 * 256];     // [d][token], granule^=(d&7) swizzle    32KB
  __shared__ u16 Ps[4 * 2048];     // per-wave dbuf 32x32 P, granule^=(row>>2)&3
  const int tid = threadIdx.x;
  const int wave = tid >> 6, lane = tid & 63;
  const int quad = lane >> 4, l15 = lane & 15;
  // bijective XCD swizzle (4096 = 8 x 512): adjacent windows share a K/V panel.
  const int raw = blockIdx.x;
  const int blk = ((raw & 7) << 9) | (raw >> 3);
  const int wi = blk & (NWIN - 1);
  const int bh = blk >> 6;                       // b*16 + h
  const long qbase = ((long)bh * SEQ_N + (long)wi * 128) * 64;
  const long kbase = ((long)bh * SEQ_N + (long)wi * 128 - 128) * 64;

  // ---- stage K into LDS: wave stages token rows [wave*64, wave*64+64) ----
  // (wi==0: rows 0..127 read harmless in-workspace garbage; their MFMAs are
  //  skipped below, so garbage never enters the math -- s stays exactly 0.)
  {
    const int sr = lane >> 3;                   // 0..7
    const int sg = ((lane & 7) ^ sr) * 8;       // inverse-swizzled source col
    const u16* g = kb + kbase + (long)(wave * 64 + sr) * 64 + sg;
#pragma unroll
    for (int i = 0; i < 8; ++i)
      load_lds16(g + i * 512, Klds + (wave * 64 + i * 8) * 64);
  }

  // ---- stage V transposed+swizzled: thread t handles key token t ----
  {
    const int t = tid;
    const bool pad = (wi == 0) && (t < 128);
    const int tg = t >> 3, t7 = t & 7;
#pragma unroll
    for (int d0 = 0; d0 < 64; d0 += 8) {
      u16x8 v8;
      if (pad) {
        v8 = (u16x8)0;
      } else {
        v8 = *(const u16x8*)(vb + (kbase + (long)t * 64 + d0));
      }
#pragma unroll
      for (int j = 0; j < 8; ++j) {
        const int d = d0 + j;
        Vt[d * 256 + (((tg ^ (d & 7)) << 3) | t7)] = v8[j];
      }
    }
  }

  // ---- Q fragments (A-operand, direct from global; rows 128B apart) ----
  bf16x8 qf[2][2];
#pragma unroll
  for (int mt = 0; mt < 2; ++mt)
#pragma unroll
    for (int kk = 0; kk < 2; ++kk)
      qf[mt][kk] = *(const bf16x8*)(qb + (qbase + (long)(wave * 32 + mt * 16 + l15) * 64 +
                                          kk * 32 + quad * 8));

  __syncthreads();  // vmcnt(0)+lgkmcnt(0)+barrier: K, V staged; Q in regs

  // ---- S = Q K^T (K frags from swizzled LDS; same values as round 3) ----
  const int axk = (quad ^ (l15 & 7)) << 4;  // byte offset within 128B row
  f32x4 s[2][16] = {};
#pragma unroll
  for (int nt = 0; nt < 16; ++nt) {
    if (!((wi == 0) && (nt < 8))) {  // zero-pad keys -> s stays 0
      const char* kr = (const char*)(Klds + (nt * 16 + l15) * 64);
      bf16x8 kf0 = *(const bf16x8*)(kr + axk);
      bf16x8 kf1 = *(const bf16x8*)(kr + (axk ^ 64));
#pragma unroll
      for (int mt = 0; mt < 2; ++mt) {
        s[mt][nt] = MFMA16(qf[mt][0], kf0, s[mt][nt]);
        s[mt][nt] = MFMA16(qf[mt][1], kf1, s[mt][nt]);
      }
    }
  }

  // ---- masked softmax over 256 keys ----
#pragma unroll
  for (int mt = 0; mt < 2; ++mt) {
#pragma unroll
    for (int r = 0; r < 4; ++r) {
      const int row = wave * 32 + mt * 16 + quad * 4 + r;
      float m = -3.0e38f;
#pragma unroll
      for (int nt = 0; nt < 16; ++nt) {
        const int col = nt * 16 + l15;
        float x = s[mt][nt][r] * 0.125f;   // dh^-0.5
        if (col > row + 128) x = -3.0e38f; // causal: key j visible iff j <= i+128
        s[mt][nt][r] = x;
        m = fmaxf(m, x);
      }
      m = fmaxf(m, __shfl_xor(m, 1));
      m = fmaxf(m, __shfl_xor(m, 2));
      m = fmaxf(m, __shfl_xor(m, 4));
      m = fmaxf(m, __shfl_xor(m, 8));
      float sum = 0.f;
#pragma unroll
      for (int nt = 0; nt < 16; ++nt) {
        float e = __expf(s[mt][nt][r] - m);
        s[mt][nt][r] = e;
        sum += e;
      }
      sum += __shfl_xor(sum, 1);
      sum += __shfl_xor(sum, 2);
      sum += __shfl_xor(sum, 4);
      sum += __shfl_xor(sum, 8);
      const float inv = 1.0f / sum;
#pragma unroll
      for (int nt = 0; nt < 16; ++nt) s[mt][nt][r] *= inv;
    }
  }

  // ---- O = P V : per 32-key chunk, swizzled P bounce through per-wave LDS ----
  f32x4 o[2][4] = {};
#pragma unroll
  for (int ks = 0; ks < 8; ++ks) {
    u16* myP = &Ps[wave * 2048 + (ks & 1) * 1024];  // 32 rows x 32 cols bf16
#pragma unroll
    for (int mt = 0; mt < 2; ++mt)
#pragma unroll
      for (int half = 0; half < 2; ++half) {
        const int nt = ks * 2 + half;
        // swizzled col: granule (half*2 + l15>>3) ^ ((row>>2)&3 == quad)
        const int colw = (((half * 2 + (l15 >> 3)) ^ quad) << 3) | (l15 & 7);
#pragma unroll
        for (int r = 0; r < 4; ++r)
          myP[(mt * 16 + quad * 4 + r) * 32 + colw] = f2bf(s[mt][nt][r]);
      }
    bf16x8 pf[2];
#pragma unroll
    for (int h = 0; h < 2; ++h)
      pf[h] = *(const bf16x8*)&myP[(h * 16 + l15) * 32 +
                                   ((quad ^ ((l15 >> 2) & 3)) << 3)];
#pragma unroll
    for (int ont = 0; ont < 4; ++ont) {
      bf16x8 vf = *(const bf16x8*)&Vt[(ont * 16 + l15) * 256 +
                                      ((((ks * 4 + quad) ^ (l15 & 7))) << 3)];
      o[0][ont] = MFMA16(pf[0], vf, o[0][ont]);
      o[1][ont] = MFMA16(pf[1], vf, o[1][ont]);
    }
  }

  // ---- write O head-major (token stride 128B) ----
#pragma unroll
  for (int mt = 0; mt < 2; ++mt)
#pragma unroll
    for (int ont = 0; ont < 4; ++ont)
#pragma unroll
      for (int r = 0; r < 4; ++r) {
        const int row = wave * 32 + mt * 16 + quad * 4 + r;
        const int col = ont * 16 + l15;
        ob[qbase + (long)row * 64 + col] = f2bf(o[mt][ont][r]);
      }
}

extern "C" void kernel_launch(void* const* d_in, const int* in_sizes, int n_in,
                              void* d_out, int out_size, void* d_ws, size_t ws_size,
                              hipStream_t stream) {
  const float* x   = (const float*)d_in[0];
  const float* wq  = (const float*)d_in[1];
  const float* wkv = (const float*)d_in[2];
  const float* wo  = (const float*)d_in[3];
  const float* bo  = (const float*)d_in[4];
  float* out = (float*)d_out;

  const size_t XE = (size_t)4 * SEQ_N * 1024;  // 33,554,432 tokens*dim elements
  u16* ws = (u16*)d_ws;
  u16* xb    = ws;            // bf16 x (reused as attention output buffer)
  u16* qbuf  = ws + XE;       // head-major [B][H][8192][64]
  u16* kbuf  = ws + 2 * XE;
  u16* vbuf  = ws + 3 * XE;
  u16* wqkvT = ws + 4 * XE;           // [3072][1024]
  u16* woT   = wqkvT + 3072 * 1024;   // [1024][1024]
  u16* obuf  = xb;                    // head-major attn output (xb dead after QKV)

  // allow 128 KiB dynamic LDS
  hipFuncSetAttribute(reinterpret_cast<const void*>(gemm8_kernel<12, 0>),
                      hipFuncAttributeMaxDynamicSharedMemorySize, 131072);
  hipFuncSetAttribute(reinterpret_cast<const void*>(gemm8_kernel<4, 1>),
                      hipFuncAttributeMaxDynamicSharedMemorySize, 131072);

  cast_bf16_kernel<<<16384, 256, 0, stream>>>(x, xb, (int)(XE / 8));
  transpose_cast_kernel<<<dim3(96, 32), 256, 0, stream>>>(wqkvT, wq, wkv, 2048);
  transpose_cast_kernel<<<dim3(32, 32), 256, 0, stream>>>(woT, wo, wo, 1024);
  // QKV: M=32768 (128 m-blocks), N=3072 (12 n-blocks) -> 1536 blocks
  gemm8_kernel<12, 0><<<1536, 512, 131072, stream>>>(xb, wqkvT, qbuf, kbuf, vbuf,
                                                     nullptr, nullptr);
  attn_kernel<<<4096, 256, 0, stream>>>(qbuf, kbuf, vbuf, obuf);
  // WO: N=1024 (4 n-blocks) -> 512 blocks; A consumed head-major
  gemm8_kernel<4, 1><<<512, 512, 131072, stream>>>(obuf, woT, nullptr, nullptr, nullptr,
                                                   out, bo);
}